// Round 1
// baseline (1243.437 us; speedup 1.0000x reference)
//
#include <hip/hip_runtime.h>

#define U_NUM   100000
#define I_NUM   50000
#define FCT     64
#define NEDGE   3200000
#define BATCH   16384
#define NROWS   (U_NUM + I_NUM)      // 150000
#define TOTSLOTS (2 * NEDGE)         // 6400000

// ---------------- CSR build ----------------

__global__ void hist_kernel(const int* __restrict__ eu, const int* __restrict__ ei,
                            int* __restrict__ cnt) {
    int t = blockIdx.x * blockDim.x + threadIdx.x;
    if (t >= NEDGE) return;
    atomicAdd(&cnt[eu[t]], 1);
    atomicAdd(&cnt[U_NUM + ei[t]], 1);
}

// per-block (1024 elems, 256 thr x 4) exclusive scan; block totals to bsum
__global__ void scan1_kernel(const int* __restrict__ cnt, int* __restrict__ out,
                             int* __restrict__ bsum) {
    __shared__ int s[256];
    int t = threadIdx.x;
    int base = blockIdx.x * 1024 + t * 4;
    int v[4];
#pragma unroll
    for (int k = 0; k < 4; k++) v[k] = (base + k < NROWS) ? cnt[base + k] : 0;
    int tot = v[0] + v[1] + v[2] + v[3];
    s[t] = tot;
    __syncthreads();
    for (int off = 1; off < 256; off <<= 1) {
        int x = (t >= off) ? s[t - off] : 0;
        __syncthreads();
        s[t] += x;
        __syncthreads();
    }
    int p = s[t] - tot;  // exclusive base for this thread
#pragma unroll
    for (int k = 0; k < 4; k++) {
        if (base + k < NROWS) out[base + k] = p;
        p += v[k];
    }
    if (t == 255) bsum[blockIdx.x] = s[255];
}

__global__ void scan2_kernel(int* __restrict__ bsum, int nb) {
    __shared__ int s[256];
    int t = threadIdx.x;
    int v = (t < nb) ? bsum[t] : 0;
    s[t] = v;
    __syncthreads();
    for (int off = 1; off < 256; off <<= 1) {
        int x = (t >= off) ? s[t - off] : 0;
        __syncthreads();
        s[t] += x;
        __syncthreads();
    }
    if (t < nb) bsum[t] = s[t] - v;  // exclusive
}

__global__ void scan3_kernel(int* __restrict__ rowptr, const int* __restrict__ bsum) {
    int i = blockIdx.x * blockDim.x + threadIdx.x;
    if (i < NROWS) rowptr[i] += bsum[i >> 10];
    if (i == NROWS) rowptr[NROWS] = TOTSLOTS;
}

__global__ void scatter_kernel(const int* __restrict__ eu, const int* __restrict__ ei,
                               const float* __restrict__ vui, const float* __restrict__ viu,
                               const int* __restrict__ rowptr, int* __restrict__ fill,
                               int2* __restrict__ csr) {
    int t = blockIdx.x * blockDim.x + threadIdx.x;
    if (t >= NEDGE) return;
    int u = eu[t], i = ei[t];
    int pu = rowptr[u] + atomicAdd(&fill[u], 1);
    csr[pu] = make_int2(i, __float_as_int(vui[t]));
    int pi = rowptr[U_NUM + i] + atomicAdd(&fill[U_NUM + i], 1);
    csr[pi] = make_int2(u, __float_as_int(viu[t]));
}

// ---------------- propagation stage: u_k = agg_users(i_{k-1}) + u_{k-1}*d_i ; sym for items ----------------

__global__ void __launch_bounds__(256) agg_kernel(
        const float* __restrict__ uprev, const float* __restrict__ iprev,
        float* __restrict__ unext, float* __restrict__ inext,
        const float* __restrict__ di, const float* __restrict__ dj,
        const int* __restrict__ rowptr, const int2* __restrict__ csr) {
    int wid = (blockIdx.x * 256 + threadIdx.x) >> 6;
    int lane = threadIdx.x & 63;
    if (wid >= NROWS) return;
    const float* selfP;
    const float* srcT;
    float* dst;
    float dscale;
    if (wid < U_NUM) {
        int r = wid;
        selfP = uprev + (size_t)r * FCT;
        srcT = iprev;
        dst = unext + (size_t)r * FCT;
        dscale = di[r];
    } else {
        int r = wid - U_NUM;
        selfP = iprev + (size_t)r * FCT;
        srcT = uprev;
        dst = inext + (size_t)r * FCT;
        dscale = dj[r];
    }
    int beg = rowptr[wid], end = rowptr[wid + 1];
    float acc = selfP[lane] * dscale;
    int e = beg;
    for (; e + 4 <= end; e += 4) {
        int2 p0 = csr[e], p1 = csr[e + 1], p2 = csr[e + 2], p3 = csr[e + 3];
        acc += __int_as_float(p0.y) * srcT[(size_t)p0.x * FCT + lane];
        acc += __int_as_float(p1.y) * srcT[(size_t)p1.x * FCT + lane];
        acc += __int_as_float(p2.y) * srcT[(size_t)p2.x * FCT + lane];
        acc += __int_as_float(p3.y) * srcT[(size_t)p3.x * FCT + lane];
    }
    for (; e < end; ++e) {
        int2 p = csr[e];
        acc += __int_as_float(p.y) * srcT[(size_t)p.x * FCT + lane];
    }
    dst[lane] = acc;
}

// ---------------- BPR head ----------------

__global__ void __launch_bounds__(256) batch_kernel(
        const float* __restrict__ u0, const float* __restrict__ u1,
        const float* __restrict__ u2, const float* __restrict__ u3,
        const float* __restrict__ i0, const float* __restrict__ i1,
        const float* __restrict__ i2, const float* __restrict__ i3,
        const int* __restrict__ user, const int* __restrict__ ita, const int* __restrict__ itb,
        float* __restrict__ out, float* __restrict__ ls, float* __restrict__ l2a) {
    int wid = (blockIdx.x * 256 + threadIdx.x) >> 6;
    int lane = threadIdx.x & 63;
    if (wid >= BATCH) return;
    size_t uo = (size_t)user[wid] * FCT + lane;
    size_t ao = (size_t)ita[wid] * FCT + lane;
    size_t bo = (size_t)itb[wid] * FCT + lane;
    const float* Ut[4] = {u0, u1, u2, u3};
    const float* It[4] = {i0, i1, i2, i3};
    float pi = 0.f, pj = 0.f, l2 = 0.f;
#pragma unroll
    for (int l = 0; l < 4; l++) {
        float ue = Ut[l][uo], ie = It[l][ao], je = It[l][bo];
        pi += ue * ie;
        pj += ue * je;
        l2 += ue * ue + ie * ie + je * je;
    }
#pragma unroll
    for (int off = 32; off; off >>= 1) {
        pi += __shfl_xor(pi, off);
        pj += __shfl_xor(pj, off);
        l2 += __shfl_xor(l2, off);
    }
    if (lane == 0) {
        out[wid] = pi;
        out[BATCH + wid] = pj;
        float x = pi - pj;
        ls[wid] = fminf(x, 0.0f) - log1pf(expf(-fabsf(x)));  // log_sigmoid(x), stable
        l2a[wid] = 0.01f * l2;
    }
}

__global__ void final_kernel(const float* __restrict__ ls, const float* __restrict__ l2a,
                             float* __restrict__ out) {
    __shared__ float s1[256], s2[256];
    int t = threadIdx.x;
    float a = 0.f, b = 0.f;
    for (int i = t; i < BATCH; i += 256) {
        a += ls[i];
        b += l2a[i];
    }
    s1[t] = a;
    s2[t] = b;
    __syncthreads();
    for (int off = 128; off; off >>= 1) {
        if (t < off) {
            s1[t] += s1[t + off];
            s2[t] += s2[t + off];
        }
        __syncthreads();
    }
    if (t == 0) {
        float loss2 = -s1[0] / (float)BATCH;
        float l2m = s2[0] / (float)BATCH;
        out[2 * BATCH] = loss2 + l2m;      // loss
        out[2 * BATCH + 1] = loss2;        // loss2
    }
}

// ---------------- launch ----------------

extern "C" void kernel_launch(void* const* d_in, const int* in_sizes, int n_in,
                              void* d_out, int out_size, void* d_ws, size_t ws_size,
                              hipStream_t stream) {
    const float* u0  = (const float*)d_in[0];
    const float* i0  = (const float*)d_in[1];
    const float* di  = (const float*)d_in[2];
    const float* dj  = (const float*)d_in[3];
    const float* vui = (const float*)d_in[4];
    const float* viu = (const float*)d_in[5];
    const int*   eu  = (const int*)d_in[6];
    const int*   ei  = (const int*)d_in[7];
    const int*   usr = (const int*)d_in[8];
    const int*   ita = (const int*)d_in[9];
    const int*   itb = (const int*)d_in[10];
    float* out = (float*)d_out;

    char* p = (char*)d_ws;
    auto alloc = [&](size_t bytes) -> char* {
        char* r = p;
        p += (bytes + 255) & ~(size_t)255;
        return r;
    };
    float* u1 = (float*)alloc((size_t)U_NUM * FCT * 4);
    float* u2 = (float*)alloc((size_t)U_NUM * FCT * 4);
    float* u3 = (float*)alloc((size_t)U_NUM * FCT * 4);
    float* i1 = (float*)alloc((size_t)I_NUM * FCT * 4);
    float* i2 = (float*)alloc((size_t)I_NUM * FCT * 4);
    float* i3 = (float*)alloc((size_t)I_NUM * FCT * 4);
    int* rowptr = (int*)alloc((size_t)(NROWS + 1) * 4);
    int* cnt    = (int*)alloc((size_t)NROWS * 4);
    int* fill   = (int*)alloc((size_t)NROWS * 4);
    int* bsum   = (int*)alloc(256 * 4);
    int2* csr   = (int2*)alloc((size_t)TOTSLOTS * 8);
    float* ls   = (float*)alloc((size_t)BATCH * 4);
    float* l2a  = (float*)alloc((size_t)BATCH * 4);

    hipMemsetAsync(cnt, 0, (size_t)NROWS * 4, stream);
    hipMemsetAsync(fill, 0, (size_t)NROWS * 4, stream);

    hist_kernel<<<(NEDGE + 255) / 256, 256, 0, stream>>>(eu, ei, cnt);
    int nb = (NROWS + 1023) / 1024;
    scan1_kernel<<<nb, 256, 0, stream>>>(cnt, rowptr, bsum);
    scan2_kernel<<<1, 256, 0, stream>>>(bsum, nb);
    scan3_kernel<<<(NROWS + 1 + 255) / 256, 256, 0, stream>>>(rowptr, bsum);
    scatter_kernel<<<(NEDGE + 255) / 256, 256, 0, stream>>>(eu, ei, vui, viu, rowptr, fill, csr);

    int aggGrid = (NROWS * 64) / 256;  // 37500
    agg_kernel<<<aggGrid, 256, 0, stream>>>(u0, i0, u1, i1, di, dj, rowptr, csr);
    agg_kernel<<<aggGrid, 256, 0, stream>>>(u1, i1, u2, i2, di, dj, rowptr, csr);
    agg_kernel<<<aggGrid, 256, 0, stream>>>(u2, i2, u3, i3, di, dj, rowptr, csr);

    batch_kernel<<<(BATCH * 64) / 256, 256, 0, stream>>>(u0, u1, u2, u3, i0, i1, i2, i3,
                                                         usr, ita, itb, out, ls, l2a);
    final_kernel<<<1, 256, 0, stream>>>(ls, l2a, out);
}